// Round 10
// baseline (128.973 us; speedup 1.0000x reference)
//
#include <hip/hip_runtime.h>
#include <hip/hip_bf16.h>

#define HWA 4096
#define CCH 256
#define NBATCH 4
#define QB 64
#define KBT 128
#define TILES_PER_BLK 16     // split-K x2: 16 of 32 tiles per block
// q pre-scaled by log2(e) in qkvgemm: exp(s-16) == exp2(s' - SMAXL2)
#define SMAXL2 23.083120654223414f
#define LOG2E  1.4426950408889634f

typedef __attribute__((ext_vector_type(8))) short bf16x8;
typedef __attribute__((ext_vector_type(4))) float f32x4;

__device__ __forceinline__ unsigned short f2bf(float f) {
    union { float f; unsigned u; } a; a.f = f;
    unsigned r = a.u + 0x7FFFu + ((a.u >> 16) & 1u);
    return (unsigned short)(r >> 16);
}
__device__ __forceinline__ float bf2f(unsigned short h) {
    union { unsigned u; float f; } a; a.u = ((unsigned)h) << 16;
    return a.f;
}
__device__ __forceinline__ void bar_lds() {
    asm volatile("s_waitcnt lgkmcnt(0)" ::: "memory");
    __builtin_amdgcn_s_barrier();
}

// ---------------- Stage 0: pack W into A-fragment-ordered hi/lo bf16 ----------------
__global__ __launch_bounds__(256) void wprep_kernel(
    const float* __restrict__ Wq, const float* __restrict__ bq,
    const float* __restrict__ Wk, const float* __restrict__ bk,
    const float* __restrict__ Wv, const float* __restrict__ bv,
    unsigned short* __restrict__ whi, unsigned short* __restrict__ wlo,
    float* __restrict__ bias_all)
{
    const int ot = blockIdx.x;
    const int t = threadIdx.x;
    const int lane = t & 63;
    const int l15 = lane & 15, g = lane >> 4;
    const int och = ot * 16 + l15;
    #pragma unroll
    for (int pass = 0; pass < 2; ++pass) {
        const int kf = (t >> 6) + 4 * pass;
        unsigned short h8[8], l8[8];
        #pragma unroll
        for (int j = 0; j < 8; ++j) {
            int c = 32 * kf + g * 8 + j;
            float v;
            if (och < 32)      v = Wq[och * CCH + c];
            else if (och < 64) v = Wk[(och - 32) * CCH + c];
            else               v = Wv[(och - 64) * CCH + c];
            unsigned short hb = f2bf(v);
            h8[j] = hb;
            l8[j] = f2bf(v - bf2f(hb));
        }
        size_t base = ((size_t)(ot * 8 + kf) * 64 + lane) * 8;
        *(bf16x8*)(whi + base) = *(bf16x8*)h8;
        *(bf16x8*)(wlo + base) = *(bf16x8*)l8;
    }
    if (ot == 0) {
        for (int i = t; i < 320; i += 256)
            bias_all[i] = (i < 32) ? bq[i] : (i < 64) ? bk[i - 32] : bv[i - 64];
    }
}

// ---------------- Stage 1: MFMA projection GEMM ----------------
// Grid 512 (XCD-swizzled), 4 waves, 2 blocks/CU. q/k written as single bf16
// stream (attn QK is 1-term); q pre-scaled by log2e.
__global__ __launch_bounds__(256) void qkvgemm_kernel(
    const float* __restrict__ x,
    const unsigned short* __restrict__ whi, const unsigned short* __restrict__ wlo,
    const float* __restrict__ bias_all,
    unsigned short* __restrict__ qb, unsigned short* __restrict__ kb,
    unsigned short* __restrict__ vb)
{
    const int t = threadIdx.x;
    const int w = t >> 6, l = t & 63, l15 = l & 15, g = l >> 4;
    const int b = blockIdx.x;
    const int logical = (b & 7) * 64 + (b >> 3);
    const int n    = logical >> 7;
    const int rem  = logical & 127;
    const int cb   = rem >> 1;
    const int half = rem & 1;
    const int col = cb * 64 + w * 16 + l15;

    bf16x8 Bh[8], Bl[8];
    #pragma unroll
    for (int kf = 0; kf < 8; ++kf) {
        unsigned short hh[8], ll[8];
        #pragma unroll
        for (int j = 0; j < 8; ++j) {
            float v = x[((size_t)(n * CCH + 32 * kf + g * 8 + j)) * HWA + col];
            unsigned short hb = f2bf(v);
            hh[j] = hb;
            ll[j] = f2bf(v - bf2f(hb));
        }
        Bh[kf] = *(bf16x8*)hh;
        Bl[kf] = *(bf16x8*)ll;
    }

    const f32x4 zero4 = {0.f, 0.f, 0.f, 0.f};
    for (int ot = half * 10; ot < half * 10 + 10; ++ot) {
        f32x4 acc = zero4;
        #pragma unroll
        for (int kf = 0; kf < 8; ++kf) {
            size_t base = ((size_t)(ot * 8 + kf) * 64 + l) * 8;
            bf16x8 Ah = *(const bf16x8*)(whi + base);
            bf16x8 Al = *(const bf16x8*)(wlo + base);
            acc = __builtin_amdgcn_mfma_f32_16x16x32_bf16(Ah, Bh[kf], acc, 0, 0, 0);
            acc = __builtin_amdgcn_mfma_f32_16x16x32_bf16(Ah, Bl[kf], acc, 0, 0, 0);
            acc = __builtin_amdgcn_mfma_f32_16x16x32_bf16(Al, Bh[kf], acc, 0, 0, 0);
        }
        f32x4 bia = *(const f32x4*)&bias_all[ot * 16 + 4 * g];
        float vv[4];
        #pragma unroll
        for (int r = 0; r < 4; ++r) vv[r] = acc[r] + bia[r];

        if (ot < 4) {
            if (ot < 2) {               // q rows: fold log2e for exp2-domain softmax
                #pragma unroll
                for (int r = 0; r < 4; ++r) vv[r] *= LOG2E;
            }
            unsigned short h4[4];
            #pragma unroll
            for (int r = 0; r < 4; ++r) h4[r] = f2bf(vv[r]);
            unsigned short* hp = (ot < 2) ? qb : kb;
            size_t base = ((size_t)(n * HWA + col)) * 32 + (ot & 1) * 16 + 4 * g;
            *(ushort4*)(hp + base) = *(ushort4*)h4;
        } else {
            #pragma unroll
            for (int r = 0; r < 4; ++r)
                vb[((size_t)(n * CCH + ot * 16 - 64 + 4 * g + r)) * HWA + col] = f2bf(vv[r]);
        }
    }
}

// ---------------- Stage 2: split-K static-max MFMA flash attention ----------------
// Grid 512 = 4n x 64qb x 2kh (XCD-swizzled: each XCD owns one (n,kh)), 8 waves,
// __launch_bounds__(512,4) -> 2 blocks/CU = 4 waves/SIMD. 1-term bf16 QK.
// asm-pinned K/V single-buffer loads (reload into dead regs after use).
// Writes bf16 partial O and f32 partial lsum; combine kernel finalizes.
__global__ __launch_bounds__(512, 4) void attn_kernel(
    const unsigned short* __restrict__ qg, const unsigned short* __restrict__ kg,
    const unsigned short* __restrict__ vg,
    unsigned short* __restrict__ opart, float* __restrict__ lpart)
{
    __shared__ char P_raw[2][16384];            // P dbuf; epilogue reuses as out_lds
    __shared__ float lsum_lds[64][9];

    const int tid = threadIdx.x;
    const int w = tid >> 6;
    const int l = tid & 63;
    const int l15 = l & 15;
    const int g = l >> 4;

    const int bid = blockIdx.x;
    const int logical = (bid & 7) * 64 + (bid >> 3);
    const int n  = logical >> 7;                 // 2 XCDs per n
    const int kh = (logical >> 6) & 1;           // constant per XCD
    const int qbk = logical & 63;
    const int q0 = qbk * QB;
    const int t0 = kh * TILES_PER_BLK;

    // Q fragments (B operand), single bf16 stream
    bf16x8 Qh[4];
    #pragma unroll
    for (int nt = 0; nt < 4; ++nt)
        Qh[nt] = *(const bf16x8*)(qg + ((size_t)(n * HWA + q0 + 16 * nt + l15)) * 32 + g * 8);

    // per-lane bases (K tile t0; V tile t0)
    const unsigned short* kbase = kg + ((size_t)(n * HWA + t0 * KBT + 16 * w + l15)) * 32 + g * 8;
    const unsigned short* vbase = vg + ((size_t)(n * CCH + 32 * w + l15)) * HWA + t0 * KBT + g * 8;
    const unsigned short* kph = kbase + (size_t)2 * KBT * 32;   // K(t0+2) onward
    const unsigned short* vp0 = vbase + KBT;                    // V(t0+1) onward
    const unsigned short* vp1 = vp0 + 16 * HWA;

    f32x4 acc[4][2] = {};
    f32x4 s_acc[4];
    float lsum[4] = {0.f, 0.f, 0.f, 0.f};
    const f32x4 zero4 = {0.f, 0.f, 0.f, 0.f};

    bf16x8 Kch;            // K for next QK (single buffer, asm-pinned)
    bf16x8 Vc[2][4];       // V for next PV (single buffer, asm-pinned)

    // ---- prologue: QK(t0), issue K(t0+1) + V(t0), expPack(t0) ----
    {
        bf16x8 k0 = *(const bf16x8*)kbase;
        #pragma unroll
        for (int nt = 0; nt < 4; ++nt)
            s_acc[nt] = __builtin_amdgcn_mfma_f32_16x16x32_bf16(k0, Qh[nt], zero4, 0, 0, 0);
    }
    asm volatile("global_load_dwordx4 %0, %1, off" : "=v"(Kch) : "v"(kbase + (size_t)KBT * 32));
    asm volatile("global_load_dwordx4 %0, %1, off"            : "=v"(Vc[0][0]) : "v"(vbase));
    asm volatile("global_load_dwordx4 %0, %1, off offset:64"  : "=v"(Vc[0][1]) : "v"(vbase));
    asm volatile("global_load_dwordx4 %0, %1, off offset:128" : "=v"(Vc[0][2]) : "v"(vbase));
    asm volatile("global_load_dwordx4 %0, %1, off offset:192" : "=v"(Vc[0][3]) : "v"(vbase));
    {
        const unsigned short* vb1 = vbase + 16 * HWA;
        asm volatile("global_load_dwordx4 %0, %1, off"            : "=v"(Vc[1][0]) : "v"(vb1));
        asm volatile("global_load_dwordx4 %0, %1, off offset:64"  : "=v"(Vc[1][1]) : "v"(vb1));
        asm volatile("global_load_dwordx4 %0, %1, off offset:128" : "=v"(Vc[1][2]) : "v"(vb1));
        asm volatile("global_load_dwordx4 %0, %1, off offset:192" : "=v"(Vc[1][3]) : "v"(vb1));
    }
    // expPack(t0) -> buf0
    #pragma unroll
    for (int nt = 0; nt < 4; ++nt) {
        float e0 = __builtin_amdgcn_exp2f(s_acc[nt][0] - SMAXL2);
        float e1 = __builtin_amdgcn_exp2f(s_acc[nt][1] - SMAXL2);
        float e2 = __builtin_amdgcn_exp2f(s_acc[nt][2] - SMAXL2);
        float e3 = __builtin_amdgcn_exp2f(s_acc[nt][3] - SMAXL2);
        lsum[nt] += (e0 + e1) + (e2 + e3);
        __hip_bfloat162 b01 = __float22bfloat162_rn(make_float2(e0, e1));
        __hip_bfloat162 b23 = __float22bfloat162_rn(make_float2(e2, e3));
        char* pbp = P_raw[0] + nt * 4096 + (w >> 1) * 1024 +
                    ((2 * (w & 1) + (g >> 1)) * 16 + l15) * 16 + (g & 1) * 8;
        *(uint2*)pbp = make_uint2(*(unsigned*)&b01, *(unsigned*)&b23);
    }
    bar_lds();                       // P(t0) visible

    // ---- body ti=0..14: {QK(t+1); reload K; PV(t)||expPack(t+1); reload V; bar} ----
    for (int ti = 0; ti < TILES_PER_BLK - 1; ++ti) {
        asm volatile("s_waitcnt vmcnt(0)" ::: "memory");   // K(t+1), V(t) arrived
        __builtin_amdgcn_sched_barrier(0);

        __builtin_amdgcn_s_setprio(1);
        #pragma unroll
        for (int nt = 0; nt < 4; ++nt)
            s_acc[nt] = __builtin_amdgcn_mfma_f32_16x16x32_bf16(Kch, Qh[nt], zero4, 0, 0, 0);

        if (ti <= TILES_PER_BLK - 3) {        // reload K(t+2) into dead Kch
            asm volatile("global_load_dwordx4 %0, %1, off" : "=v"(Kch) : "v"(kph));
            kph += (size_t)KBT * 32;
        }

        const char* rdb = P_raw[ti & 1];
        char* wrb = P_raw[(ti & 1) ^ 1];
        #pragma unroll
        for (int s = 0; s < 4; ++s) {
            bf16x8 Af[4];
            #pragma unroll
            for (int m = 0; m < 4; ++m)
                Af[m] = *(const bf16x8*)(rdb + (m * 4 + s) * 1024 + l * 16);
            #pragma unroll
            for (int m = 0; m < 4; ++m)
                #pragma unroll
                for (int ct = 0; ct < 2; ++ct)
                    acc[m][ct] = __builtin_amdgcn_mfma_f32_16x16x32_bf16(
                        Af[m], Vc[ct][s], acc[m][ct], 0, 0, 0);
            // softmax slice nt=s of tile t+1 (VALU under the MFMA pipe)
            float e0 = __builtin_amdgcn_exp2f(s_acc[s][0] - SMAXL2);
            float e1 = __builtin_amdgcn_exp2f(s_acc[s][1] - SMAXL2);
            float e2 = __builtin_amdgcn_exp2f(s_acc[s][2] - SMAXL2);
            float e3 = __builtin_amdgcn_exp2f(s_acc[s][3] - SMAXL2);
            lsum[s] += (e0 + e1) + (e2 + e3);
            __hip_bfloat162 b01 = __float22bfloat162_rn(make_float2(e0, e1));
            __hip_bfloat162 b23 = __float22bfloat162_rn(make_float2(e2, e3));
            char* pbp = wrb + s * 4096 + (w >> 1) * 1024 +
                        ((2 * (w & 1) + (g >> 1)) * 16 + l15) * 16 + (g & 1) * 8;
            *(uint2*)pbp = make_uint2(*(unsigned*)&b01, *(unsigned*)&b23);
        }
        __builtin_amdgcn_s_setprio(0);

        // reload V(t+1) into dead Vc (covered by barrier + next QK)
        asm volatile("global_load_dwordx4 %0, %1, off"            : "=v"(Vc[0][0]) : "v"(vp0));
        asm volatile("global_load_dwordx4 %0, %1, off offset:64"  : "=v"(Vc[0][1]) : "v"(vp0));
        asm volatile("global_load_dwordx4 %0, %1, off offset:128" : "=v"(Vc[0][2]) : "v"(vp0));
        asm volatile("global_load_dwordx4 %0, %1, off offset:192" : "=v"(Vc[0][3]) : "v"(vp0));
        asm volatile("global_load_dwordx4 %0, %1, off"            : "=v"(Vc[1][0]) : "v"(vp1));
        asm volatile("global_load_dwordx4 %0, %1, off offset:64"  : "=v"(Vc[1][1]) : "v"(vp1));
        asm volatile("global_load_dwordx4 %0, %1, off offset:128" : "=v"(Vc[1][2]) : "v"(vp1));
        asm volatile("global_load_dwordx4 %0, %1, off offset:192" : "=v"(Vc[1][3]) : "v"(vp1));
        vp0 += KBT; vp1 += KBT;

        bar_lds();                   // P(t+1) visible / buf reads done
    }

    // ---- epilogue: PV(last) ----
    asm volatile("s_waitcnt vmcnt(0)" ::: "memory");
    __builtin_amdgcn_sched_barrier(0);
    __builtin_amdgcn_s_setprio(1);
    #pragma unroll
    for (int s = 0; s < 4; ++s) {
        bf16x8 Af[4];
        #pragma unroll
        for (int m = 0; m < 4; ++m)
            Af[m] = *(const bf16x8*)(P_raw[(TILES_PER_BLK - 1) & 1] +
                                     (m * 4 + s) * 1024 + l * 16);
        #pragma unroll
        for (int m = 0; m < 4; ++m)
            #pragma unroll
            for (int ct = 0; ct < 2; ++ct)
                acc[m][ct] = __builtin_amdgcn_mfma_f32_16x16x32_bf16(
                    Af[m], Vc[ct][s], acc[m][ct], 0, 0, 0);
    }
    __builtin_amdgcn_s_setprio(0);

    // lsum: shfl across g, LDS across waves, write lpart
    #pragma unroll
    for (int nt = 0; nt < 4; ++nt) {
        float s = lsum[nt];
        s += __shfl_xor(s, 16);
        s += __shfl_xor(s, 32);
        lsum[nt] = s;
    }
    if (l < 16) {
        #pragma unroll
        for (int nt = 0; nt < 4; ++nt) lsum_lds[16 * nt + l][w] = lsum[nt];
    }
    bar_lds();                       // also: all PV reads of P_raw done before reuse
    if (tid < 64) {
        float lt = 0.f;
        #pragma unroll
        for (int ww = 0; ww < 8; ++ww) lt += lsum_lds[tid][ww];
        lpart[(size_t)(kh * NBATCH + n) * HWA + q0 + tid] = lt;
    }

    // partial-O store via LDS transpose (bf16)
    float (*out_lds)[265] = (float(*)[265])P_raw;   // 16x265x4B = 16.9KB < 32KB
    const size_t obase = (size_t)kh * NBATCH * CCH * HWA;
    for (int m = 0; m < 4; ++m) {
        #pragma unroll
        for (int ct = 0; ct < 2; ++ct)
            #pragma unroll
            for (int r = 0; r < 4; ++r)
                out_lds[4 * g + r][32 * w + 16 * ct + l15] = acc[m][ct][r];
        bar_lds();
        const int qi = tid & 15;
        const int cb2 = tid >> 4;
        #pragma unroll
        for (int p = 0; p < 8; ++p) {
            int c = cb2 + 32 * p;
            opart[obase + ((size_t)(n * CCH + c)) * HWA + q0 + 16 * m + qi] =
                f2bf(out_lds[qi][c]);
        }
        bar_lds();
    }
}

// ---------------- Stage 3: combine split-K partials ----------------
// out = gamma*(O0+O1)/(l0+l1) + x. Grid 4096x256, float4 per thread.
__global__ __launch_bounds__(256) void combine_kernel(
    const unsigned short* __restrict__ opart, const float* __restrict__ lpart,
    const float* __restrict__ x, const float* __restrict__ gamma_p,
    float* __restrict__ out)
{
    const int idx = blockIdx.x * 256 + threadIdx.x;    // 0..1048575
    const size_t flat = (size_t)idx * 4;
    const int n = (int)(flat >> 20);
    const int p = (int)(flat & 4095);
    const size_t KHOFF = (size_t)NBATCH * CCH * HWA;   // 4,194,304

    ushort4 a = *(const ushort4*)(opart + flat);
    ushort4 b = *(const ushort4*)(opart + KHOFF + flat);
    float4 l0 = *(const float4*)(lpart + (size_t)n * HWA + p);
    float4 l1 = *(const float4*)(lpart + (size_t)(NBATCH + n) * HWA + p);
    float4 xv = *(const float4*)(x + flat);
    const float gam = gamma_p[0];

    float4 o;
    o.x = gam * (bf2f(a.x) + bf2f(b.x)) / (l0.x + l1.x) + xv.x;
    o.y = gam * (bf2f(a.y) + bf2f(b.y)) / (l0.y + l1.y) + xv.y;
    o.z = gam * (bf2f(a.z) + bf2f(b.z)) / (l0.z + l1.z) + xv.z;
    o.w = gam * (bf2f(a.w) + bf2f(b.w)) / (l0.w + l1.w) + xv.w;
    *(float4*)(out + flat) = o;
}

extern "C" void kernel_launch(void* const* d_in, const int* in_sizes, int n_in,
                              void* d_out, int out_size, void* d_ws, size_t ws_size,
                              hipStream_t stream) {
    const float* x  = (const float*)d_in[0];
    const float* Wq = (const float*)d_in[1];
    const float* bq = (const float*)d_in[2];
    const float* Wk = (const float*)d_in[3];
    const float* bk = (const float*)d_in[4];
    const float* Wv = (const float*)d_in[5];
    const float* bv = (const float*)d_in[6];
    const float* gm = (const float*)d_in[7];
    float* out = (float*)d_out;

    float* bias_all = (float*)d_ws;                               // 320 f
    unsigned short* whi = (unsigned short*)(bias_all + 320);      // 81920
    unsigned short* wlo = whi + 81920;                            // 81920
    unsigned short* qbw = wlo + 81920;                            // 524288
    unsigned short* kbw = qbw + (size_t)NBATCH * HWA * 32;        // 524288
    unsigned short* vbw = kbw + (size_t)NBATCH * HWA * 32;        // 4,194,304
    unsigned short* opart = vbw + (size_t)NBATCH * CCH * HWA;     // 8,388,608
    float* lpart = (float*)(opart + (size_t)2 * NBATCH * CCH * HWA); // 32768 f

    hipLaunchKernelGGL(wprep_kernel, dim3(20), dim3(256), 0, stream,
                       Wq, bq, Wk, bk, Wv, bv, whi, wlo, bias_all);
    hipLaunchKernelGGL(qkvgemm_kernel, dim3(512), dim3(256), 0, stream,
                       x, whi, wlo, bias_all, qbw, kbw, vbw);
    hipLaunchKernelGGL(attn_kernel, dim3(512), dim3(512), 0, stream,
                       qbw, kbw, vbw, opart, lpart);
    hipLaunchKernelGGL(combine_kernel, dim3(4096), dim3(256), 0, stream,
                       opart, lpart, x, gm, out);
}

// Round 12
// 103.681 us; speedup vs baseline: 1.2439x; 1.2439x over previous
//
#include <hip/hip_runtime.h>
#include <hip/hip_bf16.h>

#define HWA 4096
#define CCH 256
#define NBATCH 4
#define QB 64
#define KBT 128
#define NTILES (HWA / KBT)   // 32
// q pre-scaled by log2(e) in qkvgemm: exp(s-16) == exp2(s' - SMAXL2)
#define SMAXL2 23.083120654223414f
#define LOG2E  1.4426950408889634f

typedef __attribute__((ext_vector_type(8))) short bf16x8;
typedef __attribute__((ext_vector_type(4))) float f32x4;

__device__ __forceinline__ unsigned short f2bf(float f) {
    union { float f; unsigned u; } a; a.f = f;
    unsigned r = a.u + 0x7FFFu + ((a.u >> 16) & 1u);
    return (unsigned short)(r >> 16);
}
__device__ __forceinline__ float bf2f(unsigned short h) {
    union { unsigned u; float f; } a; a.u = ((unsigned)h) << 16;
    return a.f;
}
__device__ __forceinline__ void bar_lds() {
    asm volatile("s_waitcnt lgkmcnt(0)" ::: "memory");
    __builtin_amdgcn_s_barrier();
}

// ---------------- Stage 0: pack W into A-fragment-ordered hi/lo bf16 ----------------
__global__ __launch_bounds__(256) void wprep_kernel(
    const float* __restrict__ Wq, const float* __restrict__ bq,
    const float* __restrict__ Wk, const float* __restrict__ bk,
    const float* __restrict__ Wv, const float* __restrict__ bv,
    unsigned short* __restrict__ whi, unsigned short* __restrict__ wlo,
    float* __restrict__ bias_all)
{
    const int ot = blockIdx.x;
    const int t = threadIdx.x;
    const int lane = t & 63;
    const int l15 = lane & 15, g = lane >> 4;
    const int och = ot * 16 + l15;
    #pragma unroll
    for (int pass = 0; pass < 2; ++pass) {
        const int kf = (t >> 6) + 4 * pass;
        unsigned short h8[8], l8[8];
        #pragma unroll
        for (int j = 0; j < 8; ++j) {
            int c = 32 * kf + g * 8 + j;
            float v;
            if (och < 32)      v = Wq[och * CCH + c];
            else if (och < 64) v = Wk[(och - 32) * CCH + c];
            else               v = Wv[(och - 64) * CCH + c];
            unsigned short hb = f2bf(v);
            h8[j] = hb;
            l8[j] = f2bf(v - bf2f(hb));
        }
        size_t base = ((size_t)(ot * 8 + kf) * 64 + lane) * 8;
        *(bf16x8*)(whi + base) = *(bf16x8*)h8;
        *(bf16x8*)(wlo + base) = *(bf16x8*)l8;
    }
    if (ot == 0) {
        for (int i = t; i < 320; i += 256)
            bias_all[i] = (i < 32) ? bq[i] : (i < 64) ? bk[i - 32] : bv[i - 64];
    }
}

// ---------------- Stage 1: MFMA projection GEMM ----------------
// Grid 512 (XCD-swizzled), 4 waves, 2 blocks/CU. q/k single bf16 stream
// (attn QK is 1-term); q pre-scaled by log2e. v in [n][256][hw] bf16.
__global__ __launch_bounds__(256) void qkvgemm_kernel(
    const float* __restrict__ x,
    const unsigned short* __restrict__ whi, const unsigned short* __restrict__ wlo,
    const float* __restrict__ bias_all,
    unsigned short* __restrict__ qb, unsigned short* __restrict__ kb,
    unsigned short* __restrict__ vb)
{
    const int t = threadIdx.x;
    const int w = t >> 6, l = t & 63, l15 = l & 15, g = l >> 4;
    const int b = blockIdx.x;
    const int logical = (b & 7) * 64 + (b >> 3);
    const int n    = logical >> 7;
    const int rem  = logical & 127;
    const int cb   = rem >> 1;
    const int half = rem & 1;
    const int col = cb * 64 + w * 16 + l15;

    bf16x8 Bh[8], Bl[8];
    #pragma unroll
    for (int kf = 0; kf < 8; ++kf) {
        unsigned short hh[8], ll[8];
        #pragma unroll
        for (int j = 0; j < 8; ++j) {
            float v = x[((size_t)(n * CCH + 32 * kf + g * 8 + j)) * HWA + col];
            unsigned short hb = f2bf(v);
            hh[j] = hb;
            ll[j] = f2bf(v - bf2f(hb));
        }
        Bh[kf] = *(bf16x8*)hh;
        Bl[kf] = *(bf16x8*)ll;
    }

    const f32x4 zero4 = {0.f, 0.f, 0.f, 0.f};
    for (int ot = half * 10; ot < half * 10 + 10; ++ot) {
        f32x4 acc = zero4;
        #pragma unroll
        for (int kf = 0; kf < 8; ++kf) {
            size_t base = ((size_t)(ot * 8 + kf) * 64 + l) * 8;
            bf16x8 Ah = *(const bf16x8*)(whi + base);
            bf16x8 Al = *(const bf16x8*)(wlo + base);
            acc = __builtin_amdgcn_mfma_f32_16x16x32_bf16(Ah, Bh[kf], acc, 0, 0, 0);
            acc = __builtin_amdgcn_mfma_f32_16x16x32_bf16(Ah, Bl[kf], acc, 0, 0, 0);
            acc = __builtin_amdgcn_mfma_f32_16x16x32_bf16(Al, Bh[kf], acc, 0, 0, 0);
        }
        f32x4 bia = *(const f32x4*)&bias_all[ot * 16 + 4 * g];
        float vv[4];
        #pragma unroll
        for (int r = 0; r < 4; ++r) vv[r] = acc[r] + bia[r];

        if (ot < 4) {
            if (ot < 2) {               // q rows: fold log2e for exp2-domain softmax
                #pragma unroll
                for (int r = 0; r < 4; ++r) vv[r] *= LOG2E;
            }
            unsigned short h4[4];
            #pragma unroll
            for (int r = 0; r < 4; ++r) h4[r] = f2bf(vv[r]);
            unsigned short* hp = (ot < 2) ? qb : kb;
            size_t base = ((size_t)(n * HWA + col)) * 32 + (ot & 1) * 16 + 4 * g;
            *(ushort4*)(hp + base) = *(ushort4*)h4;
        } else {
            #pragma unroll
            for (int r = 0; r < 4; ++r)
                vb[((size_t)(n * CCH + ot * 16 - 64 + 4 * g + r)) * HWA + col] = f2bf(vv[r]);
        }
    }
}

// ---------------- Stage 2: 16-wave role-split static-max MFMA flash attention ----------------
// Grid 256 (XCD-swizzled), 1024 threads = 16 waves, 1 block/CU = 4 waves/SIMD.
// Waves 0-7: QK (16 k-rows each) + exp/pack; ALL waves: PV over a 16-channel
// slice (Vc[4]=16 VGPR, acc[4]=16). One barrier/tile, P double-buffered,
// asm-pinned K/V loads reloaded into dead regs (full-iteration cover).
__global__ __launch_bounds__(1024, 4) void attn_kernel(
    const unsigned short* __restrict__ qg, const unsigned short* __restrict__ kg,
    const unsigned short* __restrict__ vg, const float* __restrict__ x,
    const float* __restrict__ gamma_p, float* __restrict__ out)
{
    __shared__ char P_raw[2][16384];            // P dbuf; epilogue reuses buf0 as out_lds
    __shared__ float lsum_lds[64][9];

    const int tid = threadIdx.x;
    const int w = tid >> 6;          // 0..15
    const int l = tid & 63;
    const int l15 = l & 15;
    const int g = l >> 4;
    const bool isqk = (w < 8);

    const int bid = blockIdx.x;
    const int logical = (bid & 7) * 32 + (bid >> 3);
    const int n  = logical >> 6;
    const int qb = logical & 63;
    const int q0 = qb * QB;

    // Q fragments (B operand), QK waves only
    bf16x8 Qh[4];
    if (isqk) {
        #pragma unroll
        for (int nt = 0; nt < 4; ++nt)
            Qh[nt] = *(const bf16x8*)(qg + ((size_t)(n * HWA + q0 + 16 * nt + l15)) * 32 + g * 8);
    }

    // per-lane bases
    const unsigned short* kbase = kg + ((size_t)(n * HWA + 16 * w + l15)) * 32 + g * 8;
    const unsigned short* vbase = vg + ((size_t)(n * CCH + 16 * w + l15)) * HWA + g * 8;
    const unsigned short* kph = kbase + (size_t)2 * KBT * 32;  // K(2) onward
    const unsigned short* vp  = vbase + KBT;                   // V(1) onward

    f32x4 acc[4] = {};               // out[16m+4g+r][16w+l15]
    f32x4 s_acc[4];
    float lsum[4] = {0.f, 0.f, 0.f, 0.f};
    const f32x4 zero4 = {0.f, 0.f, 0.f, 0.f};

    bf16x8 Kch;                      // next-tile K (QK waves)
    bf16x8 Vc[4];                    // next-tile V slice (all waves)

    // ---- prologue: QK(0), issue K(1)+V(0), expPack(0) ----
    if (isqk) {
        bf16x8 k0 = *(const bf16x8*)kbase;
        #pragma unroll
        for (int nt = 0; nt < 4; ++nt)
            s_acc[nt] = __builtin_amdgcn_mfma_f32_16x16x32_bf16(k0, Qh[nt], zero4, 0, 0, 0);
        asm volatile("global_load_dwordx4 %0, %1, off" : "=v"(Kch) : "v"(kbase + (size_t)KBT * 32));
    }
    asm volatile("global_load_dwordx4 %0, %1, off"            : "=v"(Vc[0]) : "v"(vbase));
    asm volatile("global_load_dwordx4 %0, %1, off offset:64"  : "=v"(Vc[1]) : "v"(vbase));
    asm volatile("global_load_dwordx4 %0, %1, off offset:128" : "=v"(Vc[2]) : "v"(vbase));
    asm volatile("global_load_dwordx4 %0, %1, off offset:192" : "=v"(Vc[3]) : "v"(vbase));
    if (isqk) {
        #pragma unroll
        for (int nt = 0; nt < 4; ++nt) {
            float e0 = __builtin_amdgcn_exp2f(s_acc[nt][0] - SMAXL2);
            float e1 = __builtin_amdgcn_exp2f(s_acc[nt][1] - SMAXL2);
            float e2 = __builtin_amdgcn_exp2f(s_acc[nt][2] - SMAXL2);
            float e3 = __builtin_amdgcn_exp2f(s_acc[nt][3] - SMAXL2);
            lsum[nt] += (e0 + e1) + (e2 + e3);
            __hip_bfloat162 b01 = __float22bfloat162_rn(make_float2(e0, e1));
            __hip_bfloat162 b23 = __float22bfloat162_rn(make_float2(e2, e3));
            char* pbp = P_raw[0] + nt * 4096 + (w >> 1) * 1024 +
                        ((2 * (w & 1) + (g >> 1)) * 16 + l15) * 16 + (g & 1) * 8;
            *(uint2*)pbp = make_uint2(*(unsigned*)&b01, *(unsigned*)&b23);
        }
    }
    bar_lds();                       // P(0) visible

    // ---- body t=0..30: {wait; QK(t+1); reload K; PV(t)||expPack(t+1); reload V; bar} ----
    for (int t = 0; t < NTILES - 1; ++t) {
        asm volatile("s_waitcnt vmcnt(0)" ::: "memory");   // V(t) (+K(t+1)) arrived
        __builtin_amdgcn_sched_barrier(0);

        __builtin_amdgcn_s_setprio(1);
        if (isqk) {
            #pragma unroll
            for (int nt = 0; nt < 4; ++nt)
                s_acc[nt] = __builtin_amdgcn_mfma_f32_16x16x32_bf16(Kch, Qh[nt], zero4, 0, 0, 0);
            if (t + 2 < NTILES) {
                asm volatile("global_load_dwordx4 %0, %1, off" : "=v"(Kch) : "v"(kph));
                kph += (size_t)KBT * 32;
            }
        }
        const char* rdb = P_raw[t & 1];
        char* wrb = P_raw[(t & 1) ^ 1];
        #pragma unroll
        for (int s = 0; s < 4; ++s) {
            bf16x8 Af[4];
            #pragma unroll
            for (int m = 0; m < 4; ++m)
                Af[m] = *(const bf16x8*)(rdb + (m * 4 + s) * 1024 + l * 16);
            #pragma unroll
            for (int m = 0; m < 4; ++m)
                acc[m] = __builtin_amdgcn_mfma_f32_16x16x32_bf16(Af[m], Vc[s], acc[m], 0, 0, 0);
            if (isqk) {              // softmax slice nt=s of tile t+1, under MFMA pipe
                float e0 = __builtin_amdgcn_exp2f(s_acc[s][0] - SMAXL2);
                float e1 = __builtin_amdgcn_exp2f(s_acc[s][1] - SMAXL2);
                float e2 = __builtin_amdgcn_exp2f(s_acc[s][2] - SMAXL2);
                float e3 = __builtin_amdgcn_exp2f(s_acc[s][3] - SMAXL2);
                lsum[s] += (e0 + e1) + (e2 + e3);
                __hip_bfloat162 b01 = __float22bfloat162_rn(make_float2(e0, e1));
                __hip_bfloat162 b23 = __float22bfloat162_rn(make_float2(e2, e3));
                char* pbp = wrb + s * 4096 + (w >> 1) * 1024 +
                            ((2 * (w & 1) + (g >> 1)) * 16 + l15) * 16 + (g & 1) * 8;
                *(uint2*)pbp = make_uint2(*(unsigned*)&b01, *(unsigned*)&b23);
            }
        }
        __builtin_amdgcn_s_setprio(0);

        // reload V(t+1) into dead Vc (in flight across barrier + next QK)
        asm volatile("global_load_dwordx4 %0, %1, off"            : "=v"(Vc[0]) : "v"(vp));
        asm volatile("global_load_dwordx4 %0, %1, off offset:64"  : "=v"(Vc[1]) : "v"(vp));
        asm volatile("global_load_dwordx4 %0, %1, off offset:128" : "=v"(Vc[2]) : "v"(vp));
        asm volatile("global_load_dwordx4 %0, %1, off offset:192" : "=v"(Vc[3]) : "v"(vp));
        vp += KBT;

        bar_lds();                   // P(t+1) visible / buf reads done
    }

    // ---- epilogue: PV(31) ----
    asm volatile("s_waitcnt vmcnt(0)" ::: "memory");
    __builtin_amdgcn_sched_barrier(0);
    __builtin_amdgcn_s_setprio(1);
    #pragma unroll
    for (int s = 0; s < 4; ++s) {
        bf16x8 Af[4];
        #pragma unroll
        for (int m = 0; m < 4; ++m)
            Af[m] = *(const bf16x8*)(P_raw[(NTILES - 1) & 1] + (m * 4 + s) * 1024 + l * 16);
        #pragma unroll
        for (int m = 0; m < 4; ++m)
            acc[m] = __builtin_amdgcn_mfma_f32_16x16x32_bf16(Af[m], Vc[s], acc[m], 0, 0, 0);
    }
    __builtin_amdgcn_s_setprio(0);

    // lsum: shfl across g then LDS across the 8 QK waves
    if (isqk) {
        #pragma unroll
        for (int nt = 0; nt < 4; ++nt) {
            float s = lsum[nt];
            s += __shfl_xor(s, 16);
            s += __shfl_xor(s, 32);
            lsum[nt] = s;
        }
        if (l < 16) {
            #pragma unroll
            for (int nt = 0; nt < 4; ++nt) lsum_lds[16 * nt + l][w] = lsum[nt];
        }
    }
    bar_lds();

    // out = gamma*(O/l) + x via LDS transpose (reuses P_raw buf0: PV(31) read buf1)
    float (*out_lds)[260] = (float(*)[260])P_raw;
    const float gam = gamma_p[0];
    for (int m = 0; m < 4; ++m) {
        #pragma unroll
        for (int r = 0; r < 4; ++r)
            out_lds[4 * g + r][16 * w + l15] = acc[m][r];
        bar_lds();
        const int qi = tid & 15;
        const int cb2 = tid >> 4;    // 0..63
        float lt = 0.f;
        #pragma unroll
        for (int ww = 0; ww < 8; ++ww) lt += lsum_lds[16 * m + qi][ww];
        const float li = 1.0f / lt;
        #pragma unroll
        for (int p = 0; p < 4; ++p) {
            int c = cb2 + 64 * p;
            size_t ga = ((size_t)(n * CCH + c)) * HWA + q0 + 16 * m + qi;
            out[ga] = gam * out_lds[qi][c] * li + x[ga];
        }
        bar_lds();
    }
}

extern "C" void kernel_launch(void* const* d_in, const int* in_sizes, int n_in,
                              void* d_out, int out_size, void* d_ws, size_t ws_size,
                              hipStream_t stream) {
    const float* x  = (const float*)d_in[0];
    const float* Wq = (const float*)d_in[1];
    const float* bq = (const float*)d_in[2];
    const float* Wk = (const float*)d_in[3];
    const float* bk = (const float*)d_in[4];
    const float* Wv = (const float*)d_in[5];
    const float* bv = (const float*)d_in[6];
    const float* gm = (const float*)d_in[7];
    float* out = (float*)d_out;

    float* bias_all = (float*)d_ws;                               // 320 f
    unsigned short* whi = (unsigned short*)(bias_all + 320);      // 81920
    unsigned short* wlo = whi + 81920;                            // 81920
    unsigned short* qbw = wlo + 81920;                            // 524288
    unsigned short* kbw = qbw + (size_t)NBATCH * HWA * 32;        // 524288
    unsigned short* vbw = kbw + (size_t)NBATCH * HWA * 32;        // 4,194,304

    hipLaunchKernelGGL(wprep_kernel, dim3(20), dim3(256), 0, stream,
                       Wq, bq, Wk, bk, Wv, bv, whi, wlo, bias_all);
    hipLaunchKernelGGL(qkvgemm_kernel, dim3(512), dim3(256), 0, stream,
                       x, whi, wlo, bias_all, qbw, kbw, vbw);
    hipLaunchKernelGGL(attn_kernel, dim3(256), dim3(1024), 0, stream,
                       qbw, kbw, vbw, x, gm, out);
}